// Round 3
// baseline (95.651 us; speedup 1.0000x reference)
//
#include <hip/hip_runtime.h>
#include <hip/hip_bf16.h>

#define NROWS 8192
#define DIM 256
#define NCLS 100
#define NCLS_PAD 128
#define TEMP 0.7f
#define EPSV 1e-8f
#define LMAX 512  // max rows per class (mean 82, multinomial tail << 512)

// ---------------- kernel 1: fused prototype build (no atomics, no scratch zeroing) --
// one block per padded class: scan labels -> match list -> per-dim sum -> mean ->
// norm -> write protoScaled = mean/(norm*T). Blocks c>=NCLS write zeros.
// Block NCLS_PAD-1 also zero-inits d_out for k_main's atomic (stream-ordered).
__global__ __launch_bounds__(256) void k_proto(const float* __restrict__ f,
                                               const int* __restrict__ labels,
                                               float* __restrict__ protoScaled,
                                               float* __restrict__ countf,
                                               float* __restrict__ out) {
    int c = blockIdx.x, tid = threadIdx.x;
    __shared__ int list[LMAX];
    __shared__ int nm;
    __shared__ float red[256];
    if (tid == 0) nm = 0;
    __syncthreads();
    #pragma unroll
    for (int i = 0; i < NROWS / 256; ++i) {
        int r = i * 256 + tid;
        if (labels[r] == c) {
            int idx = atomicAdd(&nm, 1);  // LDS atomic only
            if (idx < LMAX) list[idx] = r;
        }
    }
    __syncthreads();
    int n = nm < LMAX ? nm : LMAX;
    // thread t owns dim t; 8-deep unroll for memory-level parallelism
    float acc = 0.0f;
    int i = 0;
    for (; i + 8 <= n; i += 8) {
        float a0 = f[list[i + 0] * DIM + tid], a1 = f[list[i + 1] * DIM + tid];
        float a2 = f[list[i + 2] * DIM + tid], a3 = f[list[i + 3] * DIM + tid];
        float a4 = f[list[i + 4] * DIM + tid], a5 = f[list[i + 5] * DIM + tid];
        float a6 = f[list[i + 6] * DIM + tid], a7 = f[list[i + 7] * DIM + tid];
        acc += ((a0 + a1) + (a2 + a3)) + ((a4 + a5) + (a6 + a7));
    }
    for (; i < n; ++i) acc += f[list[i] * DIM + tid];
    float mean = acc / fmaxf((float)n, 1.0f);
    red[tid] = mean * mean;
    __syncthreads();
    #pragma unroll
    for (int m = 128; m > 0; m >>= 1) {
        if (tid < m) red[tid] += red[tid + m];
        __syncthreads();
    }
    float scale = 1.0f / (fmaxf(sqrtf(red[0]), EPSV) * TEMP);
    protoScaled[c * DIM + tid] = mean * scale;  // zeros for padded classes
    if (tid == 0) {
        countf[c] = (float)n;
        if (c == NCLS_PAD - 1) out[0] = 0.0f;
    }
}

// ---------------- kernel 2: dots + contrastive reduction (invf fused in) ----------
// 256 blocks x 256 thr; 32 rows x 128 classes per block, BK=32, 4x4 tile/thread.
// Row sumsq accumulated during fT staging -> invf computed in-block (no global pass).
#define BM 32
#define LDST 36

__global__ __launch_bounds__(256) void k_main(const float* __restrict__ f,
                                              const int* __restrict__ labels,
                                              const float* __restrict__ protoScaled,
                                              const float* __restrict__ countf,
                                              float* __restrict__ out) {
    __shared__ __attribute__((aligned(16))) float fT[BM * LDST];
    __shared__ __attribute__((aligned(16))) float pT[NCLS_PAD * LDST];
    __shared__ float ssred[BM * 8];
    __shared__ float invfS[BM];
    __shared__ float rs[BM * 33];
    __shared__ float dg[BM];

    int tid = threadIdx.x;
    int rb  = blockIdx.x * BM;
    int sr  = tid >> 3, sc = tid & 7;  // staging: row, float4-col
    int tx  = tid & 31, ty = tid >> 5; // compute: classes tx+32k, rows ty*4+j

    float acc[4][4];
    #pragma unroll
    for (int j = 0; j < 4; ++j)
        #pragma unroll
        for (int k = 0; k < 4; ++k) acc[j][k] = 0.0f;
    float ss = 0.0f;

    for (int kc = 0; kc < DIM; kc += 32) {
        float4 a = *(const float4*)&f[(rb + sr) * DIM + kc + sc * 4];
        *(float4*)&fT[sr * LDST + sc * 4] = a;
        ss += a.x * a.x + a.y * a.y + a.z * a.z + a.w * a.w;
        #pragma unroll
        for (int p = 0; p < 4; ++p) {
            int pr = p * 32 + sr;
            *(float4*)&pT[pr * LDST + sc * 4] =
                *(const float4*)&protoScaled[pr * DIM + kc + sc * 4];
        }
        __syncthreads();
        #pragma unroll
        for (int d4 = 0; d4 < 8; ++d4) {
            float4 fv[4], pv[4];
            #pragma unroll
            for (int j = 0; j < 4; ++j)
                fv[j] = *(const float4*)&fT[(ty * 4 + j) * LDST + d4 * 4];
            #pragma unroll
            for (int k = 0; k < 4; ++k)
                pv[k] = *(const float4*)&pT[(tx + 32 * k) * LDST + d4 * 4];
            #pragma unroll
            for (int j = 0; j < 4; ++j)
                #pragma unroll
                for (int k = 0; k < 4; ++k) {
                    acc[j][k] += fv[j].x * pv[k].x;
                    acc[j][k] += fv[j].y * pv[k].y;
                    acc[j][k] += fv[j].z * pv[k].z;
                    acc[j][k] += fv[j].w * pv[k].w;
                }
        }
        __syncthreads();
    }

    // finish invf: 8 staging partials per row
    ssred[sr * 8 + sc] = ss;
    __syncthreads();
    if (tid < BM) {
        float s = 0.0f;
        #pragma unroll
        for (int x = 0; x < 8; ++x) s += ssred[tid * 8 + x];
        invfS[tid] = 1.0f / fmaxf(sqrtf(s), EPSV);
    }
    __syncthreads();

    // epilogue: count*exp, row sums, log, diag, one atomic per block
    float invfr[4];
    int lab[4];
    #pragma unroll
    for (int j = 0; j < 4; ++j) {
        invfr[j] = invfS[ty * 4 + j];
        lab[j]   = labels[rb + ty * 4 + j];
    }
    float cf[4];
    #pragma unroll
    for (int k = 0; k < 4; ++k) cf[k] = countf[tx + 32 * k];

    #pragma unroll
    for (int j = 0; j < 4; ++j) {
        float rp = 0.0f;
        #pragma unroll
        for (int k = 0; k < 4; ++k) {
            int c = tx + 32 * k;
            float a = acc[j][k] * invfr[j];       // sim/T
            rp += cf[k] * __expf(a);              // padded classes: cf==0
            if (c == lab[j]) dg[ty * 4 + j] = a;  // unique writer per row
        }
        rs[(ty * 4 + j) * 33 + tx] = rp;
    }
    __syncthreads();

    if (tid < BM) {
        float s = 0.0f;
        #pragma unroll
        for (int x = 0; x < 32; ++x) s += rs[tid * 33 + x];
        float lossr = __logf(s) - dg[tid];
        #pragma unroll
        for (int m = 16; m > 0; m >>= 1) lossr += __shfl_xor(lossr, m);
        if (tid == 0) atomicAdd(out, lossr * (1.0f / (float)NROWS));
    }
}

// ---------------- launch: exactly 2 dispatches, no memsets ----------------
// ws floats: [0, 32768) protoScaled | [32768, 32896) countf
extern "C" void kernel_launch(void* const* d_in, const int* in_sizes, int n_in,
                              void* d_out, int out_size, void* d_ws, size_t ws_size,
                              hipStream_t stream) {
    const float* f      = (const float*)d_in[0];
    const int*   labels = (const int*)d_in[1];
    float* ws          = (float*)d_ws;
    float* protoScaled = ws;
    float* countf      = ws + 32768;

    k_proto<<<NCLS_PAD, 256, 0, stream>>>(f, labels, protoScaled, countf,
                                          (float*)d_out);
    k_main<<<NROWS / BM, 256, 0, stream>>>(f, labels, protoScaled, countf,
                                           (float*)d_out);
}

// Round 4
// 86.249 us; speedup vs baseline: 1.1090x; 1.1090x over previous
//
#include <hip/hip_runtime.h>
#include <hip/hip_bf16.h>

#define NROWS 8192
#define DIM 256
#define NCLS 100
#define NCLS_PAD 128
#define TEMP 0.7f
#define EPSV 1e-8f
#define LMAX 512  // max rows/class (mean 82, multinomial tail << 512)

typedef __attribute__((ext_vector_type(8))) short short8;
typedef __attribute__((ext_vector_type(4))) float f32x4;

// fp32 -> bf16 bits, round-to-nearest-even
static __device__ __forceinline__ short f2bf(float x) {
    union { float f; unsigned u; } c; c.f = x;
    unsigned r = (c.u + 0x7FFFu + ((c.u >> 16) & 1u)) >> 16;
    return (short)r;
}

// ---------------- kernel 1: prototype build -> bf16 protoB = mean/(|mean|*T) -------
// one block per padded class; float4 gather split 4 ways across thread groups.
__global__ __launch_bounds__(256) void k_proto(const float* __restrict__ f,
                                               const int* __restrict__ labels,
                                               unsigned short* __restrict__ protoB,
                                               float* __restrict__ countf,
                                               float* __restrict__ out) {
    int c = blockIdx.x, tid = threadIdx.x;
    __shared__ int list[LMAX];
    __shared__ int nm;
    __shared__ float4 red4[256];
    if (tid == 0) nm = 0;
    __syncthreads();
    #pragma unroll
    for (int i = 0; i < NROWS / 256; ++i) {
        int r = i * 256 + tid;
        if (labels[r] == c) {
            int idx = atomicAdd(&nm, 1);  // LDS atomic
            if (idx < LMAX) list[idx] = r;
        }
    }
    __syncthreads();
    int n = nm < LMAX ? nm : LMAX;
    int g = tid >> 6, d = tid & 63;  // group g takes list[i], i==g (mod 4); dim4 d
    float4 acc = make_float4(0.f, 0.f, 0.f, 0.f);
    int i = g;
    for (; i + 16 <= n; i += 16) {  // 4-deep MLP of b128 loads
        float4 v0 = *(const float4*)&f[list[i + 0] * DIM + d * 4];
        float4 v1 = *(const float4*)&f[list[i + 4] * DIM + d * 4];
        float4 v2 = *(const float4*)&f[list[i + 8] * DIM + d * 4];
        float4 v3 = *(const float4*)&f[list[i + 12] * DIM + d * 4];
        acc.x += (v0.x + v1.x) + (v2.x + v3.x);
        acc.y += (v0.y + v1.y) + (v2.y + v3.y);
        acc.z += (v0.z + v1.z) + (v2.z + v3.z);
        acc.w += (v0.w + v1.w) + (v2.w + v3.w);
    }
    for (; i < n; i += 4) {
        float4 v = *(const float4*)&f[list[i] * DIM + d * 4];
        acc.x += v.x; acc.y += v.y; acc.z += v.z; acc.w += v.w;
    }
    red4[tid] = acc;
    __syncthreads();
    if (tid < 64) {  // wave 0 finishes: combine 4 groups, mean, norm, write bf16
        float4 a0 = red4[d], a1 = red4[d + 64], a2 = red4[d + 128], a3 = red4[d + 192];
        float invn = 1.0f / fmaxf((float)n, 1.0f);
        float mx = (a0.x + a1.x + a2.x + a3.x) * invn;
        float my = (a0.y + a1.y + a2.y + a3.y) * invn;
        float mz = (a0.z + a1.z + a2.z + a3.z) * invn;
        float mw = (a0.w + a1.w + a2.w + a3.w) * invn;
        float ssq = mx * mx + my * my + mz * mz + mw * mw;
        #pragma unroll
        for (int m = 32; m > 0; m >>= 1) ssq += __shfl_xor(ssq, m);
        float scale = 1.0f / (fmaxf(sqrtf(ssq), EPSV) * TEMP);
        ushort4 o;
        o.x = (unsigned short)f2bf(mx * scale);
        o.y = (unsigned short)f2bf(my * scale);
        o.z = (unsigned short)f2bf(mz * scale);
        o.w = (unsigned short)f2bf(mw * scale);
        *(ushort4*)&protoB[c * DIM + d * 4] = o;  // padded classes: zeros
        if (d == 0) {
            countf[c] = (float)n;
            if (c == NCLS_PAD - 1) out[0] = 0.0f;  // init for k_main's atomic
        }
    }
}

// ---------------- kernel 2: MFMA dots + contrastive reduction, LDS-free GEMM ------
// 512 blocks x 64 thr (1 wave): 16 rows x 128 classes. A-frags straight from f
// (fp32->bf16 cvt in-reg, sumsq folded in), B-frags straight from L2-hot protoB.
__global__ __launch_bounds__(64) void k_main(const float* __restrict__ f,
                                             const int* __restrict__ labels,
                                             const unsigned short* __restrict__ protoB,
                                             const float* __restrict__ countf,
                                             float* __restrict__ out) {
    int l   = threadIdx.x;      // lane
    int rb  = blockIdx.x * 16;
    int n16 = l & 15, q = l >> 4;
    __shared__ float invfS[16];
    __shared__ float dgS[16];

    f32x4 acc[8];
    #pragma unroll
    for (int t = 0; t < 8; ++t) acc[t] = (f32x4){0.f, 0.f, 0.f, 0.f};

    // A-frag lane map: row = rb + n16, k = kc + q*8 + j  (m89/m120-verified)
    const float* arow = f + (rb + n16) * DIM + q * 8;
    float ss = 0.0f;

    #pragma unroll
    for (int kc = 0; kc < DIM; kc += 32) {
        float4 a0 = *(const float4*)(arow + kc);
        float4 a1 = *(const float4*)(arow + kc + 4);
        ss += a0.x * a0.x + a0.y * a0.y + a0.z * a0.z + a0.w * a0.w;
        ss += a1.x * a1.x + a1.y * a1.y + a1.z * a1.z + a1.w * a1.w;
        short8 af;
        af[0] = f2bf(a0.x); af[1] = f2bf(a0.y); af[2] = f2bf(a0.z); af[3] = f2bf(a0.w);
        af[4] = f2bf(a1.x); af[5] = f2bf(a1.y); af[6] = f2bf(a1.z); af[7] = f2bf(a1.w);
        short8 bf[8];
        #pragma unroll
        for (int t = 0; t < 8; ++t)  // B-frag: class = t*16+n16, k = kc + q*8 + j
            bf[t] = *(const short8*)&protoB[(t * 16 + n16) * DIM + kc + q * 8];
        #pragma unroll
        for (int t = 0; t < 8; ++t)
            acc[t] = __builtin_amdgcn_mfma_f32_16x16x32_bf16(af, bf[t], acc[t], 0, 0, 0);
    }

    // invf: lane covers row n16, k in {q*8+j + 32m} -> combine the 4 quads
    ss += __shfl_xor(ss, 16);
    ss += __shfl_xor(ss, 32);
    if (q == 0) invfS[n16] = 1.0f / fmaxf(sqrtf(ss), EPSV);
    __syncthreads();

    // C/D map: row = q*4 + reg, col = n16 + 16t
    int lab[4];
    float inv4[4];
    #pragma unroll
    for (int j = 0; j < 4; ++j) {
        lab[j]  = labels[rb + q * 4 + j];
        inv4[j] = invfS[q * 4 + j];
    }
    float rp[4] = {0.f, 0.f, 0.f, 0.f};
    #pragma unroll
    for (int t = 0; t < 8; ++t) {
        int col   = n16 + 16 * t;
        float cfv = countf[col];
        #pragma unroll
        for (int j = 0; j < 4; ++j) {
            float a = acc[t][j] * inv4[j];        // sim/T
            rp[j] += cfv * __expf(a);             // padded classes: cfv==0
            if (col == lab[j]) dgS[q * 4 + j] = a;  // unique writer per row
        }
    }
    __syncthreads();
    #pragma unroll
    for (int m = 1; m <= 8; m <<= 1) {  // 128-col sums: reduce 16 lanes of quad
        #pragma unroll
        for (int j = 0; j < 4; ++j) rp[j] += __shfl_xor(rp[j], m);
    }
    float lsum = 0.0f;
    #pragma unroll
    for (int j = 0; j < 4; ++j) lsum += __logf(rp[j]) - dgS[q * 4 + j];
    float contrib = (n16 == 0) ? lsum : 0.0f;  // one lane per quad
    contrib += __shfl_xor(contrib, 16);
    contrib += __shfl_xor(contrib, 32);
    if (l == 0) atomicAdd(out, contrib * (1.0f / (float)NROWS));
}

// ---------------- launch: 2 dispatches, no memsets ----------------
// ws: [0, 64 KB) protoB bf16 | floats at offset 16384: countf[128]
extern "C" void kernel_launch(void* const* d_in, const int* in_sizes, int n_in,
                              void* d_out, int out_size, void* d_ws, size_t ws_size,
                              hipStream_t stream) {
    const float* f      = (const float*)d_in[0];
    const int*   labels = (const int*)d_in[1];
    unsigned short* protoB = (unsigned short*)d_ws;
    float* countf          = (float*)d_ws + 16384;

    k_proto<<<NCLS_PAD, 256, 0, stream>>>(f, labels, protoB, countf, (float*)d_out);
    k_main<<<NROWS / 16, 64, 0, stream>>>(f, labels, protoB, countf, (float*)d_out);
}